// Round 7
// baseline (461.958 us; speedup 1.0000x reference)
//
#include <hip/hip_runtime.h>
#include <hip/hip_bf16.h>

// GraphNetwork GAT: B=4, N=2048, I=32, H=64, O=32, E=2, HD=2, D1=256
// R7: max-free softmax stats (8-deep load batching, no pm), 4-deep edge
// prefetch in mac. wh_a/embed/out unchanged from R6.

constexpr int B_  = 4;
constexpr int N_  = 2048;
constexpr int I_  = 32;
constexpr int H_  = 64;
constexpr int O_  = 32;
constexpr int EH_ = 4;          // E*HD combos, c = e*2 + h
constexpr int D1_ = 256;        // H*HD*E
constexpr int BN_ = B_ * N_;    // 8192
constexpr int NC_ = 16;         // i-chunks for softmax stats
constexpr int CH_ = N_ / NC_;   // 128
constexpr int TI_ = 16;         // msg rows per block (one MFMA m-tile)
constexpr int TK_ = 32;         // k-tile (one MFMA K)
constexpr int NKT_ = N_ / TK_;  // 64 k-tiles

typedef __bf16 bf16x8 __attribute__((ext_vector_type(8)));
typedef float floatx4 __attribute__((ext_vector_type(4)));

__device__ __forceinline__ unsigned short f2b(float f) {
    unsigned int u = __float_as_uint(f);
    return (unsigned short)((u + 0x7fffu + ((u >> 16) & 1u)) >> 16);
}
__device__ __forceinline__ float lrelu(float x) { return fmaxf(x, 0.2f * x); }

// ---------------------------------------------------------------- embedding
__global__ __launch_bounds__(256) void embed_kernel(
        const float* __restrict__ nodes, const float* __restrict__ W_emb,
        const float* __restrict__ b_emb, unsigned short* __restrict__ state0B) {
    int t = threadIdx.x;
    int r = t >> 6, h = t & 63;
    int bn = blockIdx.x * 4 + r;
    __shared__ float sn[4][I_];
    if (t < 4 * I_) {
        int rr = t / I_, ii = t % I_;
        sn[rr][ii] = nodes[(size_t)(blockIdx.x * 4 + rr) * I_ + ii];
    }
    __syncthreads();
    float acc = b_emb[h];
    #pragma unroll
    for (int i = 0; i < I_; ++i) acc += sn[r][i] * W_emb[i * H_ + h];
    state0B[(size_t)bn * H_ + h] = f2b(acc);
}

// ------------------------------------------------ Wf transpose/pack to bf16
template <int DIN>
__global__ __launch_bounds__(256) void wf_pack_kernel(
        const float* __restrict__ Wf, unsigned short* __restrict__ WfB) {
    int o = blockIdx.x * 256 + threadIdx.x;     // EH*64*DIN
    int k = o & (DIN - 1);
    int n = (o / DIN) & 63;
    int c = o / (DIN * 64);
    WfB[o] = f2b(Wf[((size_t)c * DIN + k) * 64 + n]);
}

// ---------------------------------------------------- Wh + a1/a2 via MFMA
template <int DIN>
__global__ __launch_bounds__(256) void wh_a_mfma_kernel(
        const unsigned short* __restrict__ stateB, const unsigned short* __restrict__ WfB,
        const float* __restrict__ w1, const float* __restrict__ b1,
        const float* __restrict__ w2, const float* __restrict__ b2,
        unsigned short* __restrict__ WhB, float* __restrict__ a1,
        float* __restrict__ a2) {
    int t = threadIdx.x;
    int lane = t & 63, wv = t >> 6;             // wv = c
    int col = lane & 15, qd = lane >> 4;
    int bn0 = blockIdx.x * TI_;                 // grid BN/16 = 512
    int b = bn0 >> 11;

    floatx4 acc[4] = {{0,0,0,0},{0,0,0,0},{0,0,0,0},{0,0,0,0}};
    const unsigned short* __restrict__ ap = stateB + (size_t)(bn0 + col) * DIN + qd * 8;
    const unsigned short* __restrict__ bp = WfB + ((size_t)(wv * 64 + col) * DIN + qd * 8);
    #pragma unroll
    for (int k0 = 0; k0 < DIN; k0 += 32) {
        bf16x8 af = *(const bf16x8*)(ap + k0);
        #pragma unroll
        for (int nt = 0; nt < 4; ++nt) {
            bf16x8 bf = *(const bf16x8*)(bp + (size_t)nt * 16 * DIN + k0);
            acc[nt] = __builtin_amdgcn_mfma_f32_16x16x32_bf16(af, bf, acc[nt], 0, 0, 0);
        }
    }
    int nb = ((bn0 & 2047) >> 3) + (qd >> 1);
    #pragma unroll
    for (int nt = 0; nt < 4; ++nt) {
        unsigned int lo = (unsigned int)f2b(acc[nt][0]) | ((unsigned int)f2b(acc[nt][1]) << 16);
        unsigned int hi = (unsigned int)f2b(acc[nt][2]) | ((unsigned int)f2b(acc[nt][3]) << 16);
        uint2 v = make_uint2(lo, hi);
        *(uint2*)(WhB + ((((size_t)(wv * B_ + b) * 256 + nb) * 64 + nt * 16 + col) * 8
                         + (qd & 1) * 4)) = v;
    }
    float p1[4] = {}, p2[4] = {};
    #pragma unroll
    for (int nt = 0; nt < 4; ++nt) {
        float w1n = w1[wv * H_ + nt * 16 + col];
        float w2n = w2[wv * H_ + nt * 16 + col];
        #pragma unroll
        for (int r = 0; r < 4; ++r) {
            p1[r] += acc[nt][r] * w1n;
            p2[r] += acc[nt][r] * w2n;
        }
    }
    #pragma unroll
    for (int m = 1; m < 16; m <<= 1)
        #pragma unroll
        for (int r = 0; r < 4; ++r) {
            p1[r] += __shfl_xor(p1[r], m, 64);
            p2[r] += __shfl_xor(p2[r], m, 64);
        }
    if (col == 0) {
        float b1c = b1[wv], b2c = b2[wv];
        #pragma unroll
        for (int r = 0; r < 4; ++r) {
            a1[(size_t)wv * BN_ + bn0 + qd * 4 + r] = p1[r] + b1c;
            a2[(size_t)wv * BN_ + bn0 + qd * 4 + r] = p2[r] + b2c;
        }
    }
}

// -------------------------------------------------- column softmax stats
// max-free: s[c,b,j] += exp(lrelu(a1[i]+a2[j]) + e). Logits bounded (~|16|),
// so fp32 sum is safe. 8-deep load batching for HBM MLP.
__global__ __launch_bounds__(256) void stats_kernel(
        const float* __restrict__ edges, const float* __restrict__ a1,
        const float* __restrict__ a2, float* __restrict__ ps) {
    int blk = blockIdx.x;                       // B*NC*(N/256) = 512
    int jt = blk & 7;
    int ic = (blk >> 3) & (NC_ - 1);
    int b  = blk >> 7;
    int t = threadIdx.x;
    int j = jt * 256 + t;
    __shared__ float sa1[EH_][CH_];
    for (int q = t; q < EH_ * CH_; q += 256) {
        int cc = q / CH_, ii = q % CH_;
        sa1[cc][ii] = a1[(size_t)cc * BN_ + b * N_ + ic * CH_ + ii];
    }
    __syncthreads();
    float a2v[EH_], s[EH_] = {};
    #pragma unroll
    for (int cc = 0; cc < EH_; ++cc)
        a2v[cc] = a2[(size_t)cc * BN_ + b * N_ + j];
    const float2* __restrict__ ep = (const float2*)edges + ((size_t)(b * N_ + ic * CH_)) * N_ + j;
    for (int i0 = 0; i0 < CH_; i0 += 8) {
        float2 u[8];
        #pragma unroll
        for (int q = 0; q < 8; ++q) u[q] = ep[(size_t)(i0 + q) * N_];
        #pragma unroll
        for (int q = 0; q < 8; ++q) {
            #pragma unroll
            for (int cc = 0; cc < EH_; ++cc) {
                float x = sa1[cc][i0 + q] + a2v[cc];
                s[cc] += __expf(lrelu(x) + ((cc < 2) ? u[q].x : u[q].y));
            }
        }
    }
    #pragma unroll
    for (int cc = 0; cc < EH_; ++cc)
        ps[((size_t)ic * EH_ + cc) * BN_ + b * N_ + j] = s[cc];
}

// combine partials -> za[c][bn] = (Z = ln S, a2)
__global__ __launch_bounds__(256) void combine_kernel(
        const float* __restrict__ ps, const float* __restrict__ a2,
        float2* __restrict__ za) {
    int q = blockIdx.x * 256 + threadIdx.x;     // EH*BN = 32768
    float S = 0.f;
    #pragma unroll
    for (int ic = 0; ic < NC_; ++ic) S += ps[(size_t)ic * EH_ * BN_ + q];
    za[q] = make_float2(__logf(S), a2[q]);
}

// ------------------------------------------------------------- MFMA MAC
// LAST=0: out = state1B (bf16 [bn][D1]); LAST=1: out = state2 (float [bn][H])
template <int LAST>
__global__ __launch_bounds__(256, 4) void mac_kernel(
        const float* __restrict__ edges, const float* __restrict__ a1,
        const float2* __restrict__ za, const unsigned short* __restrict__ WhB,
        const float* __restrict__ bias, void* __restrict__ outv) {
    int t = threadIdx.x;                    // 256
    int blk = blockIdx.x;                   // B*(N/16) = 512
    int b = blk >> 7;
    int i0 = (blk & 127) * TI_;
    int lane = t & 63, wv = t >> 6;         // wave id = c
    int ai = t >> 4;                        // att row 0..15
    int ak = (t & 15) * 2;                  // att k (even) 0..30
    int qd = lane >> 4;
    int col = lane & 15;

    __shared__ unsigned short satt[2][EH_][TI_][40];
    __shared__ float2 szq[2][EH_][TK_];
    __shared__ float sred[EH_][TI_][H_];

    float a1v[EH_];
    #pragma unroll
    for (int cc = 0; cc < EH_; ++cc)
        a1v[cc] = a1[(size_t)cc * BN_ + b * N_ + i0 + ai];

    const float4* __restrict__ ep =
        (const float4*)edges + (size_t)(b * N_ + i0 + ai) * (N_ >> 1);
    // 4-deep edge prefetch
    float4 ev[4];
    #pragma unroll
    for (int q = 0; q < 4; ++q) ev[q] = ep[q * (TK_ >> 1) + (ak >> 1)];
    if (t < 128) {
        int cc = t >> 5, kk = t & 31;
        szq[0][cc][kk] = za[(size_t)cc * BN_ + b * N_ + kk];
    }
    const unsigned short* __restrict__ whb0 =
        WhB + (size_t)(wv * B_ + b) * (256 * 512);
    bf16x8 bcur[4], bnxt[4];
    #pragma unroll
    for (int nt = 0; nt < 4; ++nt)
        bcur[nt] = *(const bf16x8*)(whb0 + ((size_t)qd * 64 + nt * 16 + col) * 8);

    floatx4 acc[4] = {{0,0,0,0},{0,0,0,0},{0,0,0,0},{0,0,0,0}};
    __syncthreads();

    for (int kt = 0; kt < NKT_; ++kt) {
        int cur = kt & 1, nxt = cur ^ 1;
        int k0n = ((kt + 1) & (NKT_ - 1)) * TK_;
        if (t < 128) {
            int cc = t >> 5, kk = t & 31;
            szq[nxt][cc][kk] = za[(size_t)cc * BN_ + b * N_ + k0n + kk];
        }
        float4 e0 = ev[kt & 3];
        #pragma unroll
        for (int cc = 0; cc < EH_; ++cc) {
            float2 z0 = szq[cur][cc][ak];
            float2 z1 = szq[cur][cc][ak + 1];
            float ea = (cc < 2) ? e0.x : e0.y;
            float eb = (cc < 2) ? e0.z : e0.w;
            float at0 = __expf(lrelu(a1v[cc] + z0.y) + ea - z0.x);
            float at1 = __expf(lrelu(a1v[cc] + z1.y) + eb - z1.x);
            unsigned int p = (unsigned int)f2b(at0) | ((unsigned int)f2b(at1) << 16);
            *(unsigned int*)&satt[cur][cc][ai][ak] = p;
        }
        // refill prefetch slot with tile kt+4
        ev[kt & 3] = ep[((kt + 4) & (NKT_ - 1)) * (TK_ >> 1) + (ak >> 1)];
        __syncthreads();
        int kb = ((kt + 1) & (NKT_ - 1)) * (TK_ >> 3);
        #pragma unroll
        for (int nt = 0; nt < 4; ++nt)
            bnxt[nt] = *(const bf16x8*)(whb0 + ((size_t)(kb + qd) * 64 + nt * 16 + col) * 8);
        bf16x8 af = *(const bf16x8*)&satt[cur][wv][col][qd * 8];
        #pragma unroll
        for (int nt = 0; nt < 4; ++nt)
            acc[nt] = __builtin_amdgcn_mfma_f32_16x16x32_bf16(af, bcur[nt], acc[nt], 0, 0, 0);
        #pragma unroll
        for (int nt = 0; nt < 4; ++nt) bcur[nt] = bnxt[nt];
    }

    if (LAST) {
        float* out = (float*)outv;
        #pragma unroll
        for (int nt = 0; nt < 4; ++nt) {
            float bv = bias[(wv & 1) * H_ + nt * 16 + col];
            #pragma unroll
            for (int r = 0; r < 4; ++r) {
                float x = acc[nt][r] + bv;
                sred[wv][qd * 4 + r][nt * 16 + col] = x > 0.f ? x : (__expf(x) - 1.f);
            }
        }
        __syncthreads();
        #pragma unroll
        for (int q = 0; q < 4; ++q) {
            int p = t + q * 256;
            int r = p >> 6, d = p & 63;
            float s = sred[0][r][d] + sred[1][r][d] + sred[2][r][d] + sred[3][r][d];
            out[((size_t)(b * N_ + i0 + r)) * H_ + d] = s * 0.25f;
        }
    } else {
        unsigned short* out = (unsigned short*)outv;
        #pragma unroll
        for (int nt = 0; nt < 4; ++nt) {
            float bv = bias[(wv & 1) * H_ + nt * 16 + col];
            #pragma unroll
            for (int r = 0; r < 4; ++r)
                out[((size_t)(b * N_ + i0 + qd * 4 + r)) * D1_ + wv * H_ + nt * 16 + col] =
                    f2b(acc[nt][r] + bv);
        }
    }
}

// ------------------------------------------------------------- final output
__global__ __launch_bounds__(256) void out_kernel(
        const float* __restrict__ state2, const float* __restrict__ W_out,
        const float* __restrict__ b_out, float* __restrict__ out) {
    int b = blockIdx.x, t = threadIdx.x;
    int d = t & 63, nc = t >> 6;
    float psum = 0.f;
    const float* sp = state2 + ((size_t)b * N_ + nc * (N_ / 4)) * H_ + d;
    for (int n = 0; n < N_ / 4; ++n) psum += sp[(size_t)n * H_];
    __shared__ float red[4][H_];
    red[nc][d] = psum;
    __syncthreads();
    if (t < H_) red[0][d] = red[0][d] + red[1][d] + red[2][d] + red[3][d];
    __syncthreads();
    if (t < O_) {
        float acc = b_out[t];
        #pragma unroll 8
        for (int dd = 0; dd < H_; ++dd)
            acc += (red[0][dd] * (1.f / N_)) * W_out[dd * O_ + t];
        out[b * O_ + t] = acc;
    }
}

extern "C" void kernel_launch(void* const* d_in, const int* in_sizes, int n_in,
                              void* d_out, int out_size, void* d_ws, size_t ws_size,
                              hipStream_t stream) {
    const float* nodes = (const float*)d_in[0];
    const float* edges = (const float*)d_in[1];
    const float* W_emb = (const float*)d_in[2];
    const float* b_emb = (const float*)d_in[3];
    const float* Wf0   = (const float*)d_in[4];
    const float* w1_0  = (const float*)d_in[5];
    const float* b1_0  = (const float*)d_in[6];
    const float* w2_0  = (const float*)d_in[7];
    const float* b2_0  = (const float*)d_in[8];
    const float* bias0 = (const float*)d_in[9];
    const float* Wf1   = (const float*)d_in[10];
    const float* w1_1  = (const float*)d_in[11];
    const float* b1_1  = (const float*)d_in[12];
    const float* w2_1  = (const float*)d_in[13];
    const float* b2_1  = (const float*)d_in[14];
    const float* bias1 = (const float*)d_in[15];
    const float* W_out = (const float*)d_in[16];
    const float* b_out = (const float*)d_in[17];

    float* ws = (float*)d_ws;
    unsigned short* state0B = (unsigned short*)ws;                  // 262144 fl
    unsigned short* state1B = (unsigned short*)(ws + 262144);       // 1048576 fl
    float* state2 = ws + 262144 + 1048576;                          // 524288 fl
    unsigned short* WhB  = (unsigned short*)(state2 + 524288);      // 1048576 fl
    unsigned short* WfB0 = (unsigned short*)(state2 + 524288 + 1048576);  // 8192 fl
    unsigned short* WfB1 = WfB0 + 16384;                            // 32768 fl
    float* a1   = state2 + 524288 + 1048576 + 8192 + 32768;         // 32768
    float* a2   = a1 + 32768;                                       // 32768
    float* psum = a2 + 32768;                                       // NC*EH*BN = 524288
    float2* za  = (float2*)(psum + 524288);                         // 65536 fl

    wf_pack_kernel<H_><<<EH_ * 64 * H_ / 256, 256, 0, stream>>>(Wf0, WfB0);
    wf_pack_kernel<D1_><<<EH_ * 64 * D1_ / 256, 256, 0, stream>>>(Wf1, WfB1);
    embed_kernel<<<BN_ / 4, 256, 0, stream>>>(nodes, W_emb, b_emb, state0B);

    // ---- layer 0
    wh_a_mfma_kernel<H_><<<BN_ / TI_, 256, 0, stream>>>(state0B, WfB0, w1_0, b1_0,
                                                        w2_0, b2_0, WhB, a1, a2);
    stats_kernel<<<B_ * NC_ * (N_ / 256), 256, 0, stream>>>(edges, a1, a2, psum);
    combine_kernel<<<EH_ * BN_ / 256, 256, 0, stream>>>(psum, a2, za);
    mac_kernel<0><<<B_ * (N_ / TI_), 256, 0, stream>>>(edges, a1, za, WhB, bias0, state1B);
    // ---- layer 1
    wh_a_mfma_kernel<D1_><<<BN_ / TI_, 256, 0, stream>>>(state1B, WfB1, w1_1, b1_1,
                                                         w2_1, b2_1, WhB, a1, a2);
    stats_kernel<<<B_ * NC_ * (N_ / 256), 256, 0, stream>>>(edges, a1, a2, psum);
    combine_kernel<<<EH_ * BN_ / 256, 256, 0, stream>>>(psum, a2, za);
    mac_kernel<1><<<B_ * (N_ / TI_), 256, 0, stream>>>(edges, a1, za, WhB, bias1, state2);

    out_kernel<<<B_, 256, 0, stream>>>(state2, W_out, b_out, (float*)d_out);
}